// Round 1
// baseline (47096.786 us; speedup 1.0000x reference)
//
#include <hip/hip_runtime.h>
#include <cstdint>
#include <cfloat>
#include <cmath>

// ---------------------------------------------------------------------------
// MossTTS local transformer decode. B=256,H=1024,L=4,HKV=8,D=64,I=4096,V=1027,C=16.
// seq_len==1 -> attention == repeat(v); w_q/w_k/q_norm/k_norm dead.
// This round: GEMMs rebuilt as broadcast-B kernels. Old 64x64 outer-product
// tiles paid 2B of LDS per FLOP (ds_read_b128-bound at ~45% VALU). New
// structure: 256 thr = 128 rows x 2 col-halves; B-tile read via wave-uniform
// broadcast (conflict-free), A-tile via XOR-swizzled (slot^row&7) b128 reads
// at the 8-words/bank floor; double-buffered reg->LDS staging with one
// barrier per k-tile. Per-output fmaf chain order and split-K boundaries are
// bitwise-identical to the previous (passing, absmax 0.0) kernel.
// ---------------------------------------------------------------------------

#define PARTITIONABLE 1

namespace {
constexpr int B = 256, H = 1024, L = 4;
constexpr int I = 4096, V = 1027, C = 16;
constexpr int KV = 512;
}

// ------------------------------ threefry2x32 -------------------------------
__device__ __forceinline__ void tf2x32(uint32_t k0, uint32_t k1,
                                       uint32_t x0, uint32_t x1,
                                       uint32_t& o0, uint32_t& o1) {
  uint32_t k2 = k0 ^ k1 ^ 0x1BD11BDAu;
  x0 += k0; x1 += k1;
#define TFR(r) { x0 += x1; x1 = (x1 << r) | (x1 >> (32 - r)); x1 ^= x0; }
  TFR(13) TFR(15) TFR(26) TFR(6)
  x0 += k1; x1 += k2 + 1u;
  TFR(17) TFR(29) TFR(16) TFR(24)
  x0 += k2; x1 += k0 + 2u;
  TFR(13) TFR(15) TFR(26) TFR(6)
  x0 += k0; x1 += k1 + 3u;
  TFR(17) TFR(29) TFR(16) TFR(24)
  x0 += k1; x1 += k2 + 4u;
  TFR(13) TFR(15) TFR(26) TFR(6)
  x0 += k2; x1 += k0 + 5u;
#undef TFR
  o0 = x0; o1 = x1;
}

__device__ __forceinline__ float gumbel_for(uint32_t k0, uint32_t k1,
                                            uint32_t idx) {
  uint32_t o0, o1, bits;
  tf2x32(k0, k1, 0u, idx, o0, o1);
  bits = o0 ^ o1;
  float f = __uint_as_float((bits >> 9) | 0x3f800000u) - 1.0f;
  float u = fmaxf(FLT_MIN, f + FLT_MIN);
  return -logf(-logf(u));
}

// --------------------------- small fused kernels ---------------------------
// h = backbone ; r[b] = rsqrt(mean(h^2)+eps). Block per row.
__global__ __launch_bounds__(256) void copy_rms_k(const float* __restrict__ src,
                                                  float* __restrict__ h,
                                                  float* __restrict__ r) {
  int b = blockIdx.x, tid = threadIdx.x;
  float4 v = *(const float4*)&src[(size_t)b * H + tid * 4];
  *(float4*)&h[(size_t)b * H + tid * 4] = v;
  float s = v.x * v.x + v.y * v.y + v.z * v.z + v.w * v.w;
  for (int off = 32; off > 0; off >>= 1) s += __shfl_down(s, off, 64);
  __shared__ float red[4];
  if ((tid & 63) == 0) red[tid >> 6] = s;
  __syncthreads();
  if (tid == 0) {
    float t = red[0] + red[1] + red[2] + red[3];
    r[b] = 1.0f / sqrtf(t * (1.0f / 1024.0f) + 1e-6f);
  }
}

// Wo' [L][512][1024]: fold the repeat-KV gather: Wo'[c,n] = Wo[kb*128+j,n] + Wo[kb*128+j+64,n]
__global__ __launch_bounds__(256) void fold_k(const float* __restrict__ wo,
                                              float* __restrict__ wof) {
  int blk = blockIdx.x;             // l*512 + c
  int l = blk >> 9, c = blk & 511;
  int kb = c >> 6, jl = c & 63;
  const float* w = wo + (size_t)l * H * H;
  int k1 = kb * 128 + jl, k2 = k1 + 64;
  int j = threadIdx.x * 4;
  float4 a = *(const float4*)&w[(size_t)k1 * H + j];
  float4 bq = *(const float4*)&w[(size_t)k2 * H + j];
  float4 o = {a.x + bq.x, a.y + bq.y, a.z + bq.z, a.w + bq.w};
  *(float4*)&wof[((size_t)l * KV + c) * H + j] = o;
}

// ------------------------ broadcast-B GEMM kernel --------------------------
// Block: 256 threads = 128 rows x 2 col-halves; computes rows [rb,rb+128) x
// cols [bn,bn+16) of A@B (FGU: also A@Bu with fused silu combine -> Cp=m).
// A-tile [128][32] in LDS, XOR-swizzled: float4 slot s of row r stored at
// slot s^(r&7) -> read pattern is uniform 8 words/bank (b128 floor).
// B-tile [32][16] in LDS, read same-address per wave (broadcast, no
// conflict). Split-K partial written at Cp + z*256*N (reduced elsewhere in
// fixed order). Accumulation: k strictly ascending, fmaf -> bitwise equal to
// the previous kernel's per-output chain.
template <bool NORM, bool GATHER, bool BT, bool BOUND, bool FGU>
__global__ __launch_bounds__(256) void gemvb_k(
    const float* __restrict__ A, int lda,
    const float* __restrict__ rv, const float* __restrict__ wn,
    const float* __restrict__ Bm, const float* __restrict__ Bu, int ldb,
    float* __restrict__ Cp, int N, int Kslice) {
  __shared__ __align__(16) float As[2][128 * 32];
  __shared__ __align__(16) float Bs[2][32 * 16];
  __shared__ __align__(16) float Us[FGU ? 2 : 1][32 * 16];
  const int tid = threadIdx.x;
  const int bn = blockIdx.x * 16;
  const int rb = blockIdx.y * 128;
  const int ks0 = blockIdx.z * Kslice;
  const int r0 = tid & 127, ch = tid >> 7;   // row r0, cols bn+ch*8..+7
  const int arow = tid >> 3, aslot = tid & 7; // staging: 8 lanes/row, 8 slots
  const int nt = Kslice >> 5;

  float4 a_st[4];
  float b_st[2], u_st[2];

  auto load_tile = [&](int kt) {
    const int kbase = ks0 + kt * 32;
    const int k = kbase + aslot * 4;
    const int col = GATHER ? (((k >> 7) << 6) | (k & 63)) : k;
#pragma unroll
    for (int q = 0; q < 4; ++q) {
      const int row = 32 * q + arow;
      float4 av = *(const float4*)&A[(size_t)(rb + row) * lda + col];
      if (NORM) {
        float sc = rv[rb + row];
        float4 wv = *(const float4*)&wn[k];
        av.x *= sc * wv.x; av.y *= sc * wv.y;
        av.z *= sc * wv.z; av.w *= sc * wv.w;
      }
      a_st[q] = av;
    }
#pragma unroll
    for (int pass = 0; pass < 2; ++pass) {
      const int idx = pass * 256 + tid;
      if (!BT) {
        const int kI = idx >> 4, c = idx & 15;
        const int n = bn + c;
        b_st[pass] = (!BOUND || n < N) ? Bm[(size_t)(kbase + kI) * ldb + n] : 0.f;
        if constexpr (FGU) u_st[pass] = Bu[(size_t)(kbase + kI) * ldb + n];
      } else {
        const int kI = idx & 31, c = idx >> 5;
        const int n = bn + c;
        b_st[pass] = (!BOUND || n < N) ? Bm[(size_t)n * ldb + kbase + kI] : 0.f;
      }
    }
  };
  auto store_tile = [&](int p) {
#pragma unroll
    for (int q = 0; q < 4; ++q) {
      const int row = 32 * q + arow;
      *(float4*)&As[p][row * 32 + ((aslot ^ (row & 7)) << 2)] = a_st[q];
    }
#pragma unroll
    for (int pass = 0; pass < 2; ++pass) {
      const int idx = pass * 256 + tid;
      const int kI = BT ? (idx & 31) : (idx >> 4);
      const int c  = BT ? (idx >> 5) : (idx & 15);
      Bs[p][kI * 16 + c] = b_st[pass];
      if constexpr (FGU) Us[p][kI * 16 + c] = u_st[pass];
    }
  };

  float4 ac0 = {0.f, 0.f, 0.f, 0.f}, ac1 = {0.f, 0.f, 0.f, 0.f};
  float4 gu0 = {0.f, 0.f, 0.f, 0.f}, gu1 = {0.f, 0.f, 0.f, 0.f};

  load_tile(0);
  store_tile(0);
  __syncthreads();
  int p = 0;
  const int xr = r0 & 7;
  for (int t = 0; t < nt; ++t) {
    if (t + 1 < nt) load_tile(t + 1);   // issue next-tile loads before compute
    const float* ap = &As[p][r0 * 32];
#pragma unroll
    for (int s = 0; s < 8; ++s) {
      const float4 av = *(const float4*)&ap[(s ^ xr) << 2];  // kk = 4s..4s+3
      const float ar[4] = {av.x, av.y, av.z, av.w};
#pragma unroll
      for (int qq = 0; qq < 4; ++qq) {
        const int kk = 4 * s + qq;
        const float* bp = &Bs[p][kk * 16 + ch * 8];
        const float4 b0 = *(const float4*)&bp[0];
        const float4 b1 = *(const float4*)&bp[4];
        ac0.x = fmaf(ar[qq], b0.x, ac0.x);
        ac0.y = fmaf(ar[qq], b0.y, ac0.y);
        ac0.z = fmaf(ar[qq], b0.z, ac0.z);
        ac0.w = fmaf(ar[qq], b0.w, ac0.w);
        ac1.x = fmaf(ar[qq], b1.x, ac1.x);
        ac1.y = fmaf(ar[qq], b1.y, ac1.y);
        ac1.z = fmaf(ar[qq], b1.z, ac1.z);
        ac1.w = fmaf(ar[qq], b1.w, ac1.w);
        if constexpr (FGU) {
          const float* up = &Us[p][kk * 16 + ch * 8];
          const float4 u0 = *(const float4*)&up[0];
          const float4 u1 = *(const float4*)&up[4];
          gu0.x = fmaf(ar[qq], u0.x, gu0.x);
          gu0.y = fmaf(ar[qq], u0.y, gu0.y);
          gu0.z = fmaf(ar[qq], u0.z, gu0.z);
          gu0.w = fmaf(ar[qq], u0.w, gu0.w);
          gu1.x = fmaf(ar[qq], u1.x, gu1.x);
          gu1.y = fmaf(ar[qq], u1.y, gu1.y);
          gu1.z = fmaf(ar[qq], u1.z, gu1.z);
          gu1.w = fmaf(ar[qq], u1.w, gu1.w);
        }
      }
    }
    if (t + 1 < nt) store_tile(p ^ 1);  // writes land after compute; one barrier/tile
    __syncthreads();
    p ^= 1;
  }

  const int row = rb + r0;
  const int cb = bn + ch * 8;
  if constexpr (!FGU) {
    float* dst = Cp + (size_t)blockIdx.z * (size_t)256 * N + (size_t)row * N + cb;
    if (!BOUND) {
      *(float4*)&dst[0] = ac0;
      *(float4*)&dst[4] = ac1;
    } else {
      const float v0[8] = {ac0.x, ac0.y, ac0.z, ac0.w,
                           ac1.x, ac1.y, ac1.z, ac1.w};
#pragma unroll
      for (int j = 0; j < 8; ++j)
        if (cb + j < N) dst[j] = v0[j];
    }
  } else {
    const float g[8] = {ac0.x, ac0.y, ac0.z, ac0.w,
                        ac1.x, ac1.y, ac1.z, ac1.w};
    const float u[8] = {gu0.x, gu0.y, gu0.z, gu0.w,
                        gu1.x, gu1.y, gu1.z, gu1.w};
    float o[8];
#pragma unroll
    for (int j = 0; j < 8; ++j) {
      const float s = 1.0f / (1.0f + expf(-g[j]));
      o[j] = g[j] * s * u[j];
    }
    float* dst = Cp + (size_t)row * N + cb;
    *(float4*)&dst[0] = *(const float4*)&o[0];
    *(float4*)&dst[4] = *(const float4*)&o[4];
  }
}

// ------------------------------ reductions ---------------------------------
__global__ __launch_bounds__(256) void red_v_k(const float* __restrict__ part,
                                               float* __restrict__ v, int S) {
  int i4 = (blockIdx.x * 256 + threadIdx.x) * 4;
  float4 s = {0.f, 0.f, 0.f, 0.f};
  for (int ss = 0; ss < S; ++ss) {
    float4 p = *(const float4*)&part[(size_t)ss * (256 * KV) + i4];
    s.x += p.x; s.y += p.y; s.z += p.z; s.w += p.w;
  }
  *(float4*)&v[i4] = s;
}

// h += sum(partials) ; r[b] = rsqrt(mean(h^2)+eps). Block per row, N=1024.
__global__ __launch_bounds__(256) void red_add_rms_k(const float* __restrict__ part,
                                                     float* __restrict__ h,
                                                     float* __restrict__ r, int S) {
  int b = blockIdx.x, tid = threadIdx.x;
  size_t off = (size_t)b * H + tid * 4;
  float4 a = *(const float4*)&h[off];
  for (int ss = 0; ss < S; ++ss) {
    float4 p = *(const float4*)&part[(size_t)ss * (256 * H) + off];
    a.x += p.x; a.y += p.y; a.z += p.z; a.w += p.w;
  }
  *(float4*)&h[off] = a;
  float s = a.x * a.x + a.y * a.y + a.z * a.z + a.w * a.w;
  for (int o = 32; o > 0; o >>= 1) s += __shfl_down(s, o, 64);
  __shared__ float red[4];
  if ((tid & 63) == 0) red[tid >> 6] = s;
  __syncthreads();
  if (tid == 0) {
    float t = red[0] + red[1] + red[2] + red[3];
    r[b] = 1.0f / sqrtf(t * (1.0f / 1024.0f) + 1e-6f);
  }
}

// --------------------------- head: reduce+reppen+sample+embed --------------
__global__ __launch_bounds__(256) void head_k(
    const float* __restrict__ part, int S,
    const int* __restrict__ gh, const int* __restrict__ gen_step_p,
    int step, const float* __restrict__ embed_next,
    float* __restrict__ h, float* __restrict__ r,
    int* __restrict__ out) {
  constexpr int TOPK = 30;
  constexpr int KMAX = 64;
  const int b = blockIdx.x, tid = threadIdx.x;
  __shared__ float sl[V];
  __shared__ float rv_[256]; __shared__ int ri[256];
  __shared__ float topv[TOPK]; __shared__ int topi[TOPK];
  __shared__ float kv[KMAX]; __shared__ int ki[KMAX]; __shared__ int keepf[KMAX];
  __shared__ uint32_t skey[2];
  __shared__ int scnt, sn, stok;
  __shared__ float redf[4];

  if (tid == 0) {
    uint32_t o0, o1;
    tf2x32(0u, 1234u, 0u, (uint32_t)step, o0, o1);
    skey[0] = o0; skey[1] = o1;
    scnt = 0;
  }
  // sum split-K partials of the logits row
  for (int v = tid; v < V; v += 256) {
    float s = 0.f;
    for (int ss = 0; ss < S; ++ss)
      s += part[(size_t)ss * (256 * V) + (size_t)b * V + v];
    sl[v] = s;
  }
  __syncthreads();
  // repetition penalty (read-all-then-write .set semantics; dup writes identical)
  int gs = *gen_step_p;
  int cnt = gs < 50 ? gs : 50;
  int start = gs - cnt;
  int tkn = -1; float val = 0.f;
  if (tid < cnt) {
    tkn = gh[(size_t)b * 200 * C + (size_t)(start + tid) * C + step];
    val = sl[tkn];
  }
  __syncthreads();
  if (tid < cnt) sl[tkn] = (val < 0.f) ? val * 1.1f : val / 1.1f;
  __syncthreads();
  for (int v = tid; v < V; v += 256) sl[v] = sl[v] / 0.8f;
  __syncthreads();

  // iterative top-30 (argmax, lowest-index tiebreak)
  for (int it = 0; it < TOPK; ++it) {
    float bv = -INFINITY; int bi = 0x7fffffff;
    for (int v = tid; v < V; v += 256) {
      float x = sl[v];
      if (x > bv) { bv = x; bi = v; }
    }
    rv_[tid] = bv; ri[tid] = bi;
    __syncthreads();
    for (int s = 128; s > 0; s >>= 1) {
      if (tid < s) {
        float ov = rv_[tid + s]; int oi = ri[tid + s];
        if (ov > rv_[tid] || (ov == rv_[tid] && oi < ri[tid])) { rv_[tid] = ov; ri[tid] = oi; }
      }
      __syncthreads();
    }
    if (tid == 0) { topv[it] = rv_[0]; topi[it] = ri[0]; sl[ri[0]] = -INFINITY; }
    __syncthreads();
  }
  if (tid < TOPK) sl[topi[tid]] = topv[tid];
  __syncthreads();
  const float thr = topv[TOPK - 1];
  for (int v = tid; v < V; v += 256) {
    if (sl[v] >= thr) {
      int p = atomicAdd(&scnt, 1);
      if (p < KMAX) { kv[p] = sl[v]; ki[p] = v; }
    }
  }
  __syncthreads();

  if (tid == 0) {
    int n = scnt < KMAX ? scnt : KMAX;
    for (int a = 1; a < n; ++a) {  // stable ascending (value,index) sort
      float cv = kv[a]; int ci = ki[a];
      int p = a - 1;
      while (p >= 0 && (kv[p] > cv || (kv[p] == cv && ki[p] > ci))) {
        kv[p + 1] = kv[p]; ki[p + 1] = ki[p]; --p;
      }
      kv[p + 1] = cv; ki[p + 1] = ci;
    }
    float mx = kv[n - 1];
    float denom = 0.f;
    for (int j = 0; j < n; ++j) denom += expf(kv[j] - mx);
    float c = 0.f;
    for (int j = 0; j < n; ++j) {
      float p = expf(kv[j] - mx) / denom;
      c += p;
      keepf[j] = ((double)c > 0.4) ? 1 : 0;
    }
    sn = n;
  }
  __syncthreads();

  int n = sn;
  rv_[tid] = -INFINITY; ri[tid] = 0x7fffffff;
  if (tid < n && keepf[tid]) {
    uint32_t idx = (uint32_t)b * (uint32_t)V + (uint32_t)ki[tid];
    float g = gumbel_for(skey[0], skey[1], idx);
    rv_[tid] = kv[tid] + g;
    ri[tid] = ki[tid];
  }
  __syncthreads();
  for (int s = 128; s > 0; s >>= 1) {
    if (tid < s) {
      float ov = rv_[tid + s]; int oi = ri[tid + s];
      if (ov > rv_[tid] || (ov == rv_[tid] && oi < ri[tid])) { rv_[tid] = ov; ri[tid] = oi; }
    }
    __syncthreads();
  }
  if (tid == 0) {
    stok = ri[0];
    out[(size_t)b * C + step] = ri[0];
  }
  __syncthreads();

  // next-step embedding + rms scale, fused
  if (embed_next != nullptr) {
    int tok = stok;
    float4 e = *(const float4*)&embed_next[(size_t)tok * H + tid * 4];
    *(float4*)&h[(size_t)b * H + tid * 4] = e;
    float s = e.x * e.x + e.y * e.y + e.z * e.z + e.w * e.w;
    for (int o = 32; o > 0; o >>= 1) s += __shfl_down(s, o, 64);
    if ((tid & 63) == 0) redf[tid >> 6] = s;
    __syncthreads();
    if (tid == 0) {
      float t = redf[0] + redf[1] + redf[2] + redf[3];
      r[b] = 1.0f / sqrtf(t * (1.0f / 1024.0f) + 1e-6f);
    }
  }
}

// ------------------------------ launch -------------------------------------
extern "C" void kernel_launch(void* const* d_in, const int* in_sizes, int n_in,
                              void* d_out, int out_size, void* d_ws, size_t ws_size,
                              hipStream_t stream) {
  const float* backbone = (const float*)d_in[0];
  const int*   gh       = (const int*)d_in[1];
  const int*   gen_step = (const int*)d_in[2];
  const float* embed    = (const float*)d_in[3];
  const float* lm       = (const float*)d_in[4];
  const float* w_in     = (const float*)d_in[5];
  // d_in[6]=w_q, d_in[7]=w_k, d_in[9]=q_norm, d_in[10]=k_norm dead (seq_len==1)
  const float* w_v      = (const float*)d_in[8];
  const float* w_o      = (const float*)d_in[11];
  const float* w_post   = (const float*)d_in[12];
  const float* w_g      = (const float*)d_in[13];
  const float* w_u      = (const float*)d_in[14];
  const float* w_d      = (const float*)d_in[15];
  const float* fnorm    = (const float*)d_in[16];
  int* out = (int*)d_out;
  float* ws = (float*)d_ws;

  // big path needs 5,642,752 floats (~22.6MB); small path fits proven 7.87MB
  const bool big = ws_size >= (size_t)22600000;
  float* h    = ws;                                   // 262144
  float* v    = ws + 262144;                          // 131072
  float* m    = ws + 393216;                          // 1048576
  float* wof  = big ? ws + 1441792 : nullptr;         // 2097152 (big only)
  float* part = big ? ws + 3538944 : ws + 1441792;    // 2103296 / 524288
  float* r    = big ? ws + 5642240 : ws + 1966080;    // 256

  const int S1 = big ? 16 : 4;
  const int S2 = big ? 8 : 2;
  const int S4 = big ? 8 : 2;
  const int S5 = big ? 8 : 1;

  copy_rms_k<<<dim3(256), dim3(256), 0, stream>>>(backbone, h, r);
  if (big) fold_k<<<dim3(2048), dim3(256), 0, stream>>>(w_o, wof);

  for (int i = 0; i < C; ++i) {
    for (int l = 0; l < L; ++l) {
      // v = rms(h)*wi @ Wv   [256,1024]x[1024,512], split-K
      gemvb_k<true, false, false, false, false>
          <<<dim3(KV / 16, 2, S1), dim3(256), 0, stream>>>(
          h, H, r, w_in + (size_t)l * H, w_v + (size_t)l * H * KV, nullptr, KV,
          part, KV, H / S1);
      red_v_k<<<dim3(128), dim3(256), 0, stream>>>(part, v, S1);
      // h += v @ Wo' (folded, K=512) or gather path (small)
      if (big)
        gemvb_k<false, false, false, false, false>
            <<<dim3(H / 16, 2, S2), dim3(256), 0, stream>>>(
            v, KV, nullptr, nullptr, wof + (size_t)l * KV * H, nullptr, H,
            part, H, KV / S2);
      else
        gemvb_k<false, true, false, false, false>
            <<<dim3(H / 16, 2, S2), dim3(256), 0, stream>>>(
            v, KV, nullptr, nullptr, w_o + (size_t)l * H * H, nullptr, H,
            part, H, H / S2);
      red_add_rms_k<<<dim3(256), dim3(256), 0, stream>>>(part, h, r, S2);
      // m = silu(x2@Wg)*(x2@Wu), x2 = rms(h)*wp fused; full K, silu fused
      gemvb_k<true, false, false, false, true>
          <<<dim3(I / 16, 2, 1), dim3(256), 0, stream>>>(
          h, H, r, w_post + (size_t)l * H,
          w_g + (size_t)l * H * I, w_u + (size_t)l * H * I, I, m, I, H);
      // h += m @ Wd   [256,4096]x[4096,1024], split-K
      gemvb_k<false, false, false, false, false>
          <<<dim3(H / 16, 2, S4), dim3(256), 0, stream>>>(
          m, I, nullptr, nullptr, w_d + (size_t)l * I * H, nullptr, H,
          part, H, I / S4);
      red_add_rms_k<<<dim3(256), dim3(256), 0, stream>>>(part, h, r, S4);
    }
    // logits partials = rms(h)*fnorm @ lm[i]^T  (BT, N=1027 bounds)
    gemvb_k<true, false, true, true, false>
        <<<dim3((V + 15) / 16, 2, S5), dim3(256), 0, stream>>>(
        h, H, r, fnorm, lm + (size_t)i * V * H, nullptr, H, part, V, H / S5);
    head_k<<<dim3(256), dim3(256), 0, stream>>>(
        part, S5, gh, gen_step, i,
        (i < C - 1) ? embed + (size_t)(i + 1) * V * H : nullptr,
        h, r, out);
  }
}

// Round 2
// 14072.060 us; speedup vs baseline: 3.3468x; 3.3468x over previous
//
#include <hip/hip_runtime.h>
#include <cstdint>
#include <cfloat>
#include <cmath>

// ---------------------------------------------------------------------------
// MossTTS local transformer decode. B=256,H=1024,L=4,HKV=8,D=64,I=4096,V=1027,C=16.
// seq_len==1 -> attention == repeat(v); w_q/w_k/q_norm/k_norm dead.
// Round 2: revert to proven R0 structure (47ms broadcast rewrite failed: 2x
// LDS insts/FMA + nt=2 pipelines). Change ONLY thread ownership for
// occupancy: 32x64 tiles (gemm32_k, grid.y=8 -> 1024+ blocks = 4 blk/CU)
// for Wv/Wo/Wd/logits, and 64x16 tiles for gu (grid 256x4 = 1024 blocks).
// Per-output fmaf chains, split-K boundaries, NORM/silu expressions are
// bitwise-identical to the proven 10.66ms kernel -> absmax 0.0 preserved.
// ---------------------------------------------------------------------------

#define PARTITIONABLE 1

namespace {
constexpr int B = 256, H = 1024, L = 4;
constexpr int I = 4096, V = 1027, C = 16;
constexpr int KV = 512;
}

// ------------------------------ threefry2x32 -------------------------------
__device__ __forceinline__ void tf2x32(uint32_t k0, uint32_t k1,
                                       uint32_t x0, uint32_t x1,
                                       uint32_t& o0, uint32_t& o1) {
  uint32_t k2 = k0 ^ k1 ^ 0x1BD11BDAu;
  x0 += k0; x1 += k1;
#define TFR(r) { x0 += x1; x1 = (x1 << r) | (x1 >> (32 - r)); x1 ^= x0; }
  TFR(13) TFR(15) TFR(26) TFR(6)
  x0 += k1; x1 += k2 + 1u;
  TFR(17) TFR(29) TFR(16) TFR(24)
  x0 += k2; x1 += k0 + 2u;
  TFR(13) TFR(15) TFR(26) TFR(6)
  x0 += k0; x1 += k1 + 3u;
  TFR(17) TFR(29) TFR(16) TFR(24)
  x0 += k1; x1 += k2 + 4u;
  TFR(13) TFR(15) TFR(26) TFR(6)
  x0 += k2; x1 += k0 + 5u;
#undef TFR
  o0 = x0; o1 = x1;
}

__device__ __forceinline__ float gumbel_for(uint32_t k0, uint32_t k1,
                                            uint32_t idx) {
  uint32_t o0, o1, bits;
  tf2x32(k0, k1, 0u, idx, o0, o1);
  bits = o0 ^ o1;
  float f = __uint_as_float((bits >> 9) | 0x3f800000u) - 1.0f;
  float u = fmaxf(FLT_MIN, f + FLT_MIN);
  return -logf(-logf(u));
}

// --------------------------- small fused kernels ---------------------------
// h = backbone ; r[b] = rsqrt(mean(h^2)+eps). Block per row.
__global__ __launch_bounds__(256) void copy_rms_k(const float* __restrict__ src,
                                                  float* __restrict__ h,
                                                  float* __restrict__ r) {
  int b = blockIdx.x, tid = threadIdx.x;
  float4 v = *(const float4*)&src[(size_t)b * H + tid * 4];
  *(float4*)&h[(size_t)b * H + tid * 4] = v;
  float s = v.x * v.x + v.y * v.y + v.z * v.z + v.w * v.w;
  for (int off = 32; off > 0; off >>= 1) s += __shfl_down(s, off, 64);
  __shared__ float red[4];
  if ((tid & 63) == 0) red[tid >> 6] = s;
  __syncthreads();
  if (tid == 0) {
    float t = red[0] + red[1] + red[2] + red[3];
    r[b] = 1.0f / sqrtf(t * (1.0f / 1024.0f) + 1e-6f);
  }
}

// Wo' [L][512][1024]: fold the repeat-KV gather: Wo'[c,n] = Wo[kb*128+j,n] + Wo[kb*128+j+64,n]
__global__ __launch_bounds__(256) void fold_k(const float* __restrict__ wo,
                                              float* __restrict__ wof) {
  int blk = blockIdx.x;             // l*512 + c
  int l = blk >> 9, c = blk & 511;
  int kb = c >> 6, jl = c & 63;
  const float* w = wo + (size_t)l * H * H;
  int k1 = kb * 128 + jl, k2 = k1 + 64;
  int j = threadIdx.x * 4;
  float4 a = *(const float4*)&w[(size_t)k1 * H + j];
  float4 bq = *(const float4*)&w[(size_t)k2 * H + j];
  float4 o = {a.x + bq.x, a.y + bq.y, a.z + bq.z, a.w + bq.w};
  *(float4*)&wof[((size_t)l * KV + c) * H + j] = o;
}

// ------------------------------ GEMM 32x64x32 ------------------------------
// Split-K partial GEMM, 32-row tiles for occupancy (grid.y=8 -> 1024 blocks
// = 4 blocks/CU = 16 waves/CU). Thread = 2 rows x 4 cols. Per-output fmaf
// chain (ascending k) identical to the proven 64x64 version. A is [256,lda];
// if NORM, A_logical = h*r[row]*wn[k]. If GATHER, A column =
// ((k>>7)<<6)|(k&63). B normal [K,N] or BT [N,K]. Partial C at Cp + z*256*N.
template <bool NORM, bool GATHER, bool BT, bool BOUND>
__global__ __launch_bounds__(256) void gemm32_k(
    const float* __restrict__ A, int lda,
    const float* __restrict__ rv, const float* __restrict__ wn,
    const float* __restrict__ Bm, int ldb,
    float* __restrict__ Cp, int N, int Kslice) {
  __shared__ __align__(16) float As[32][36];
  __shared__ __align__(16) float Bs[32][68];
  const int tid = threadIdx.x;
  const int tx = tid & 15, ty = tid >> 4;   // 4 cols, 2 rows per thread
  const int bm = blockIdx.y * 32;
  const int bn = blockIdx.x * 64;
  const int ks0 = blockIdx.z * Kslice;
  float4 acc[2];
  acc[0] = float4{0.f, 0.f, 0.f, 0.f};
  acc[1] = float4{0.f, 0.f, 0.f, 0.f};

  for (int k0 = 0; k0 < Kslice; k0 += 32) {
    const int kbase = ks0 + k0;
    {
      // A-tile: 32 rows x 32 k = 256 float4, one per thread
      int rI = tid >> 3, c = tid & 7;
      int k = kbase + c * 4;
      int col = GATHER ? (((k >> 7) << 6) | (k & 63)) : k;
      float4 av = *(const float4*)&A[(size_t)(bm + rI) * lda + col];
      if (NORM) {
        float sc = rv[bm + rI];
        float4 wv = *(const float4*)&wn[k];
        av.x *= sc * wv.x; av.y *= sc * wv.y;
        av.z *= sc * wv.z; av.w *= sc * wv.w;
      }
      As[c * 4 + 0][rI] = av.x; As[c * 4 + 1][rI] = av.y;
      As[c * 4 + 2][rI] = av.z; As[c * 4 + 3][rI] = av.w;
    }
#pragma unroll
    for (int s = 0; s < 2; ++s) {
      int slot = tid + s * 256;
      if (!BT) {
        int kI = slot >> 4, c4 = slot & 15;
        float4 bv = *(const float4*)&Bm[(size_t)(kbase + kI) * ldb + bn + c4 * 4];
        *(float4*)&Bs[kI][c4 * 4] = bv;
      } else {
        int nI = slot >> 3, c = slot & 7;
        int n = bn + nI;
        float4 bv = {0.f, 0.f, 0.f, 0.f};
        if (!BOUND || n < N)
          bv = *(const float4*)&Bm[(size_t)n * ldb + kbase + c * 4];
        Bs[c * 4 + 0][nI] = bv.x; Bs[c * 4 + 1][nI] = bv.y;
        Bs[c * 4 + 2][nI] = bv.z; Bs[c * 4 + 3][nI] = bv.w;
      }
    }
    __syncthreads();
#pragma unroll
    for (int kk = 0; kk < 32; ++kk) {
      float2 a = *(const float2*)&As[kk][ty * 2];
      float4 b = *(const float4*)&Bs[kk][tx * 4];
      acc[0].x = fmaf(a.x, b.x, acc[0].x);
      acc[0].y = fmaf(a.x, b.y, acc[0].y);
      acc[0].z = fmaf(a.x, b.z, acc[0].z);
      acc[0].w = fmaf(a.x, b.w, acc[0].w);
      acc[1].x = fmaf(a.y, b.x, acc[1].x);
      acc[1].y = fmaf(a.y, b.y, acc[1].y);
      acc[1].z = fmaf(a.y, b.z, acc[1].z);
      acc[1].w = fmaf(a.y, b.w, acc[1].w);
    }
    __syncthreads();
  }
  float* base = Cp + (size_t)blockIdx.z * 256 * N;
#pragma unroll
  for (int i = 0; i < 2; ++i) {
    int row = bm + ty * 2 + i;
    int colb = bn + tx * 4;
    if (!BOUND) {
      *(float4*)&base[(size_t)row * N + colb] = acc[i];
    } else {
      float vals[4] = {acc[i].x, acc[i].y, acc[i].z, acc[i].w};
      for (int j = 0; j < 4; ++j)
        if (colb + j < N) base[(size_t)row * N + colb + j] = vals[j];
    }
  }
}

// -------------------- fused gate/up GEMM, 64x16x32, silu --------------------
// m = silu(x@Wg) * (x@Wu); x = h*r*wn fused in staging. Full K, no split.
// 64 rows x 16 cols per block -> grid (256,4) = 1024 blocks = 4 blocks/CU.
// Thread = 2 rows x 2 cols x 2 mats = 8 FMA/kk vs 3 broadcast LDS reads.
__global__ __launch_bounds__(256) void gemm_gu_k(
    const float* __restrict__ hm, const float* __restrict__ rv,
    const float* __restrict__ wn,
    const float* __restrict__ Bg, const float* __restrict__ Bu,
    float* __restrict__ Mo) {
  __shared__ __align__(16) float As[32][68];
  __shared__ __align__(16) float Gs[32][20];
  __shared__ __align__(16) float Us[32][20];
  const int tid = threadIdx.x;
  const int tx = tid & 7, ty = tid >> 3;     // 2 cols, 2 rows per thread
  const int bm = blockIdx.y * 64;
  const int bn = blockIdx.x * 16;
  float2 ag[2], au[2];
#pragma unroll
  for (int i = 0; i < 2; ++i) { ag[i] = float2{0.f, 0.f}; au[i] = float2{0.f, 0.f}; }

  for (int k0 = 0; k0 < H; k0 += 32) {
#pragma unroll
    for (int s = 0; s < 2; ++s) {
      int slot = tid + s * 256;
      int rI = slot >> 3, c = slot & 7;
      int k = k0 + c * 4;
      float4 av = *(const float4*)&hm[(size_t)(bm + rI) * H + k];
      float sc = rv[bm + rI];
      float4 wv = *(const float4*)&wn[k];
      av.x *= sc * wv.x; av.y *= sc * wv.y;
      av.z *= sc * wv.z; av.w *= sc * wv.w;
      As[c * 4 + 0][rI] = av.x; As[c * 4 + 1][rI] = av.y;
      As[c * 4 + 2][rI] = av.z; As[c * 4 + 3][rI] = av.w;
    }
    {
      int kI = tid >> 3, c2 = tid & 7;
      float2 gv = *(const float2*)&Bg[(size_t)(k0 + kI) * I + bn + c2 * 2];
      float2 uv = *(const float2*)&Bu[(size_t)(k0 + kI) * I + bn + c2 * 2];
      *(float2*)&Gs[kI][c2 * 2] = gv;
      *(float2*)&Us[kI][c2 * 2] = uv;
    }
    __syncthreads();
#pragma unroll
    for (int kk = 0; kk < 32; ++kk) {
      float2 a = *(const float2*)&As[kk][ty * 2];
      float2 g = *(const float2*)&Gs[kk][tx * 2];
      float2 u = *(const float2*)&Us[kk][tx * 2];
      ag[0].x = fmaf(a.x, g.x, ag[0].x);
      ag[0].y = fmaf(a.x, g.y, ag[0].y);
      ag[1].x = fmaf(a.y, g.x, ag[1].x);
      ag[1].y = fmaf(a.y, g.y, ag[1].y);
      au[0].x = fmaf(a.x, u.x, au[0].x);
      au[0].y = fmaf(a.x, u.y, au[0].y);
      au[1].x = fmaf(a.y, u.x, au[1].x);
      au[1].y = fmaf(a.y, u.y, au[1].y);
    }
    __syncthreads();
  }
#pragma unroll
  for (int i = 0; i < 2; ++i) {
    int row = bm + ty * 2 + i;
    int col = bn + tx * 2;
    float g0 = ag[i].x, g1 = ag[i].y;
    float s0 = 1.0f / (1.0f + expf(-g0));
    float s1 = 1.0f / (1.0f + expf(-g1));
    float2 o = {g0 * s0 * au[i].x, g1 * s1 * au[i].y};
    *(float2*)&Mo[(size_t)row * I + col] = o;
  }
}

// ------------------------------ reductions ---------------------------------
__global__ __launch_bounds__(256) void red_v_k(const float* __restrict__ part,
                                               float* __restrict__ v, int S) {
  int i4 = (blockIdx.x * 256 + threadIdx.x) * 4;
  float4 s = {0.f, 0.f, 0.f, 0.f};
  for (int ss = 0; ss < S; ++ss) {
    float4 p = *(const float4*)&part[(size_t)ss * (256 * KV) + i4];
    s.x += p.x; s.y += p.y; s.z += p.z; s.w += p.w;
  }
  *(float4*)&v[i4] = s;
}

// h += sum(partials) ; r[b] = rsqrt(mean(h^2)+eps). Block per row, N=1024.
__global__ __launch_bounds__(256) void red_add_rms_k(const float* __restrict__ part,
                                                     float* __restrict__ h,
                                                     float* __restrict__ r, int S) {
  int b = blockIdx.x, tid = threadIdx.x;
  size_t off = (size_t)b * H + tid * 4;
  float4 a = *(const float4*)&h[off];
  for (int ss = 0; ss < S; ++ss) {
    float4 p = *(const float4*)&part[(size_t)ss * (256 * H) + off];
    a.x += p.x; a.y += p.y; a.z += p.z; a.w += p.w;
  }
  *(float4*)&h[off] = a;
  float s = a.x * a.x + a.y * a.y + a.z * a.z + a.w * a.w;
  for (int o = 32; o > 0; o >>= 1) s += __shfl_down(s, o, 64);
  __shared__ float red[4];
  if ((tid & 63) == 0) red[tid >> 6] = s;
  __syncthreads();
  if (tid == 0) {
    float t = red[0] + red[1] + red[2] + red[3];
    r[b] = 1.0f / sqrtf(t * (1.0f / 1024.0f) + 1e-6f);
  }
}

// --------------------------- head: reduce+reppen+sample+embed --------------
__global__ __launch_bounds__(256) void head_k(
    const float* __restrict__ part, int S,
    const int* __restrict__ gh, const int* __restrict__ gen_step_p,
    int step, const float* __restrict__ embed_next,
    float* __restrict__ h, float* __restrict__ r,
    int* __restrict__ out) {
  constexpr int TOPK = 30;
  constexpr int KMAX = 64;
  const int b = blockIdx.x, tid = threadIdx.x;
  __shared__ float sl[V];
  __shared__ float rv_[256]; __shared__ int ri[256];
  __shared__ float topv[TOPK]; __shared__ int topi[TOPK];
  __shared__ float kv[KMAX]; __shared__ int ki[KMAX]; __shared__ int keepf[KMAX];
  __shared__ uint32_t skey[2];
  __shared__ int scnt, sn, stok;
  __shared__ float redf[4];

  if (tid == 0) {
    uint32_t o0, o1;
    tf2x32(0u, 1234u, 0u, (uint32_t)step, o0, o1);
    skey[0] = o0; skey[1] = o1;
    scnt = 0;
  }
  // sum split-K partials of the logits row
  for (int v = tid; v < V; v += 256) {
    float s = 0.f;
    for (int ss = 0; ss < S; ++ss)
      s += part[(size_t)ss * (256 * V) + (size_t)b * V + v];
    sl[v] = s;
  }
  __syncthreads();
  // repetition penalty (read-all-then-write .set semantics; dup writes identical)
  int gs = *gen_step_p;
  int cnt = gs < 50 ? gs : 50;
  int start = gs - cnt;
  int tkn = -1; float val = 0.f;
  if (tid < cnt) {
    tkn = gh[(size_t)b * 200 * C + (size_t)(start + tid) * C + step];
    val = sl[tkn];
  }
  __syncthreads();
  if (tid < cnt) sl[tkn] = (val < 0.f) ? val * 1.1f : val / 1.1f;
  __syncthreads();
  for (int v = tid; v < V; v += 256) sl[v] = sl[v] / 0.8f;
  __syncthreads();

  // iterative top-30 (argmax, lowest-index tiebreak)
  for (int it = 0; it < TOPK; ++it) {
    float bv = -INFINITY; int bi = 0x7fffffff;
    for (int v = tid; v < V; v += 256) {
      float x = sl[v];
      if (x > bv) { bv = x; bi = v; }
    }
    rv_[tid] = bv; ri[tid] = bi;
    __syncthreads();
    for (int s = 128; s > 0; s >>= 1) {
      if (tid < s) {
        float ov = rv_[tid + s]; int oi = ri[tid + s];
        if (ov > rv_[tid] || (ov == rv_[tid] && oi < ri[tid])) { rv_[tid] = ov; ri[tid] = oi; }
      }
      __syncthreads();
    }
    if (tid == 0) { topv[it] = rv_[0]; topi[it] = ri[0]; sl[ri[0]] = -INFINITY; }
    __syncthreads();
  }
  if (tid < TOPK) sl[topi[tid]] = topv[tid];
  __syncthreads();
  const float thr = topv[TOPK - 1];
  for (int v = tid; v < V; v += 256) {
    if (sl[v] >= thr) {
      int p = atomicAdd(&scnt, 1);
      if (p < KMAX) { kv[p] = sl[v]; ki[p] = v; }
    }
  }
  __syncthreads();

  if (tid == 0) {
    int n = scnt < KMAX ? scnt : KMAX;
    for (int a = 1; a < n; ++a) {  // stable ascending (value,index) sort
      float cv = kv[a]; int ci = ki[a];
      int p = a - 1;
      while (p >= 0 && (kv[p] > cv || (kv[p] == cv && ki[p] > ci))) {
        kv[p + 1] = kv[p]; ki[p + 1] = ki[p]; --p;
      }
      kv[p + 1] = cv; ki[p + 1] = ci;
    }
    float mx = kv[n - 1];
    float denom = 0.f;
    for (int j = 0; j < n; ++j) denom += expf(kv[j] - mx);
    float c = 0.f;
    for (int j = 0; j < n; ++j) {
      float p = expf(kv[j] - mx) / denom;
      c += p;
      keepf[j] = ((double)c > 0.4) ? 1 : 0;
    }
    sn = n;
  }
  __syncthreads();

  int n = sn;
  rv_[tid] = -INFINITY; ri[tid] = 0x7fffffff;
  if (tid < n && keepf[tid]) {
    uint32_t idx = (uint32_t)b * (uint32_t)V + (uint32_t)ki[tid];
    float g = gumbel_for(skey[0], skey[1], idx);
    rv_[tid] = kv[tid] + g;
    ri[tid] = ki[tid];
  }
  __syncthreads();
  for (int s = 128; s > 0; s >>= 1) {
    if (tid < s) {
      float ov = rv_[tid + s]; int oi = ri[tid + s];
      if (ov > rv_[tid] || (ov == rv_[tid] && oi < ri[tid])) { rv_[tid] = ov; ri[tid] = oi; }
    }
    __syncthreads();
  }
  if (tid == 0) {
    stok = ri[0];
    out[(size_t)b * C + step] = ri[0];
  }
  __syncthreads();

  // next-step embedding + rms scale, fused
  if (embed_next != nullptr) {
    int tok = stok;
    float4 e = *(const float4*)&embed_next[(size_t)tok * H + tid * 4];
    *(float4*)&h[(size_t)b * H + tid * 4] = e;
    float s = e.x * e.x + e.y * e.y + e.z * e.z + e.w * e.w;
    for (int o = 32; o > 0; o >>= 1) s += __shfl_down(s, o, 64);
    if ((tid & 63) == 0) redf[tid >> 6] = s;
    __syncthreads();
    if (tid == 0) {
      float t = redf[0] + redf[1] + redf[2] + redf[3];
      r[b] = 1.0f / sqrtf(t * (1.0f / 1024.0f) + 1e-6f);
    }
  }
}

// ------------------------------ launch -------------------------------------
extern "C" void kernel_launch(void* const* d_in, const int* in_sizes, int n_in,
                              void* d_out, int out_size, void* d_ws, size_t ws_size,
                              hipStream_t stream) {
  const float* backbone = (const float*)d_in[0];
  const int*   gh       = (const int*)d_in[1];
  const int*   gen_step = (const int*)d_in[2];
  const float* embed    = (const float*)d_in[3];
  const float* lm       = (const float*)d_in[4];
  const float* w_in     = (const float*)d_in[5];
  // d_in[6]=w_q, d_in[7]=w_k, d_in[9]=q_norm, d_in[10]=k_norm dead (seq_len==1)
  const float* w_v      = (const float*)d_in[8];
  const float* w_o      = (const float*)d_in[11];
  const float* w_post   = (const float*)d_in[12];
  const float* w_g      = (const float*)d_in[13];
  const float* w_u      = (const float*)d_in[14];
  const float* w_d      = (const float*)d_in[15];
  const float* fnorm    = (const float*)d_in[16];
  int* out = (int*)d_out;
  float* ws = (float*)d_ws;

  // big path needs 5,642,752 floats (~22.6MB); small path fits proven 7.87MB
  const bool big = ws_size >= (size_t)22600000;
  float* h    = ws;                                   // 262144
  float* v    = ws + 262144;                          // 131072
  float* m    = ws + 393216;                          // 1048576
  float* wof  = big ? ws + 1441792 : nullptr;         // 2097152 (big only)
  float* part = big ? ws + 3538944 : ws + 1441792;    // 2103296 / 524288
  float* r    = big ? ws + 5642240 : ws + 1966080;    // 256

  const int S1 = big ? 16 : 4;
  const int S2 = big ? 8 : 2;
  const int S4 = big ? 8 : 2;
  const int S5 = big ? 8 : 1;

  copy_rms_k<<<dim3(256), dim3(256), 0, stream>>>(backbone, h, r);
  if (big) fold_k<<<dim3(2048), dim3(256), 0, stream>>>(w_o, wof);

  for (int i = 0; i < C; ++i) {
    for (int l = 0; l < L; ++l) {
      // v = rms(h)*wi @ Wv   [256,1024]x[1024,512], split-K
      gemm32_k<true, false, false, false><<<dim3(8, 8, S1), dim3(256), 0, stream>>>(
          h, H, r, w_in + (size_t)l * H, w_v + (size_t)l * H * KV, KV,
          part, KV, H / S1);
      red_v_k<<<dim3(128), dim3(256), 0, stream>>>(part, v, S1);
      // h += v @ Wo' (folded, K=512) or gather path (small)
      if (big)
        gemm32_k<false, false, false, false><<<dim3(16, 8, S2), dim3(256), 0, stream>>>(
            v, KV, nullptr, nullptr, wof + (size_t)l * KV * H, H,
            part, H, KV / S2);
      else
        gemm32_k<false, true, false, false><<<dim3(16, 8, S2), dim3(256), 0, stream>>>(
            v, KV, nullptr, nullptr, w_o + (size_t)l * H * H, H,
            part, H, H / S2);
      red_add_rms_k<<<dim3(256), dim3(256), 0, stream>>>(part, h, r, S2);
      // m = silu(x2@Wg)*(x2@Wu), x2 = rms(h)*wp fused; no split, silu fused
      gemm_gu_k<<<dim3(256, 4), dim3(256), 0, stream>>>(
          h, r, w_post + (size_t)l * H,
          w_g + (size_t)l * H * I, w_u + (size_t)l * H * I, m);
      // h += m @ Wd   [256,4096]x[4096,1024], split-K
      gemm32_k<false, false, false, false><<<dim3(16, 8, S4), dim3(256), 0, stream>>>(
          m, I, nullptr, nullptr, w_d + (size_t)l * I * H, H,
          part, H, I / S4);
      red_add_rms_k<<<dim3(256), dim3(256), 0, stream>>>(part, h, r, S4);
    }
    // logits partials = rms(h)*fnorm @ lm[i]^T  (BT, N=1027 bounds)
    gemm32_k<true, false, true, true><<<dim3(17, 8, S5), dim3(256), 0, stream>>>(
        h, H, r, fnorm, lm + (size_t)i * V * H, H, part, V, H / S5);
    head_k<<<dim3(256), dim3(256), 0, stream>>>(
        part, S5, gh, gen_step, i,
        (i < C - 1) ? embed + (size_t)(i + 1) * V * H : nullptr,
        h, r, out);
  }
}

// Round 3
// 13432.990 us; speedup vs baseline: 3.5061x; 1.0476x over previous
//
#include <hip/hip_runtime.h>
#include <cstdint>
#include <cfloat>
#include <cmath>

// ---------------------------------------------------------------------------
// MossTTS local transformer decode. B=256,H=1024,L=4,HKV=8,D=64,I=4096,V=1027,C=16.
// seq_len==1 -> attention == repeat(v); w_q/w_k/q_norm/k_norm dead.
// Round 3: R0 structure restored verbatim (proven 10.66ms; R1 broadcast=47ms,
// R2 smaller-tiles=14.1ms both regressed -> intensity-per-LDS-read is the
// lever). Single change: gemm_gu_k rebuilt as 64x64 JOINT G/U tile
// (4x4x2mats = 32 FMA/kk vs 3 ds_read_b128), double-buffered LDS with
// register prefetch (1 barrier/tile, nt=32). Per-output fmaf chains,
// split-K boundaries, NORM/silu expressions bitwise-identical to R0.
// ---------------------------------------------------------------------------

#define PARTITIONABLE 1

namespace {
constexpr int B = 256, H = 1024, L = 4;
constexpr int I = 4096, V = 1027, C = 16;
constexpr int KV = 512;
}

// ------------------------------ threefry2x32 -------------------------------
__device__ __forceinline__ void tf2x32(uint32_t k0, uint32_t k1,
                                       uint32_t x0, uint32_t x1,
                                       uint32_t& o0, uint32_t& o1) {
  uint32_t k2 = k0 ^ k1 ^ 0x1BD11BDAu;
  x0 += k0; x1 += k1;
#define TFR(r) { x0 += x1; x1 = (x1 << r) | (x1 >> (32 - r)); x1 ^= x0; }
  TFR(13) TFR(15) TFR(26) TFR(6)
  x0 += k1; x1 += k2 + 1u;
  TFR(17) TFR(29) TFR(16) TFR(24)
  x0 += k2; x1 += k0 + 2u;
  TFR(13) TFR(15) TFR(26) TFR(6)
  x0 += k0; x1 += k1 + 3u;
  TFR(17) TFR(29) TFR(16) TFR(24)
  x0 += k1; x1 += k2 + 4u;
  TFR(13) TFR(15) TFR(26) TFR(6)
  x0 += k2; x1 += k0 + 5u;
#undef TFR
  o0 = x0; o1 = x1;
}

__device__ __forceinline__ float gumbel_for(uint32_t k0, uint32_t k1,
                                            uint32_t idx) {
  uint32_t o0, o1, bits;
  tf2x32(k0, k1, 0u, idx, o0, o1);
  bits = o0 ^ o1;
  float f = __uint_as_float((bits >> 9) | 0x3f800000u) - 1.0f;
  float u = fmaxf(FLT_MIN, f + FLT_MIN);
  return -logf(-logf(u));
}

// --------------------------- small fused kernels ---------------------------
// h = backbone ; r[b] = rsqrt(mean(h^2)+eps). Block per row.
__global__ __launch_bounds__(256) void copy_rms_k(const float* __restrict__ src,
                                                  float* __restrict__ h,
                                                  float* __restrict__ r) {
  int b = blockIdx.x, tid = threadIdx.x;
  float4 v = *(const float4*)&src[(size_t)b * H + tid * 4];
  *(float4*)&h[(size_t)b * H + tid * 4] = v;
  float s = v.x * v.x + v.y * v.y + v.z * v.z + v.w * v.w;
  for (int off = 32; off > 0; off >>= 1) s += __shfl_down(s, off, 64);
  __shared__ float red[4];
  if ((tid & 63) == 0) red[tid >> 6] = s;
  __syncthreads();
  if (tid == 0) {
    float t = red[0] + red[1] + red[2] + red[3];
    r[b] = 1.0f / sqrtf(t * (1.0f / 1024.0f) + 1e-6f);
  }
}

// Wo' [L][512][1024]: fold the repeat-KV gather: Wo'[c,n] = Wo[kb*128+j,n] + Wo[kb*128+j+64,n]
__global__ __launch_bounds__(256) void fold_k(const float* __restrict__ wo,
                                              float* __restrict__ wof) {
  int blk = blockIdx.x;             // l*512 + c
  int l = blk >> 9, c = blk & 511;
  int kb = c >> 6, jl = c & 63;
  const float* w = wo + (size_t)l * H * H;
  int k1 = kb * 128 + jl, k2 = k1 + 64;
  int j = threadIdx.x * 4;
  float4 a = *(const float4*)&w[(size_t)k1 * H + j];
  float4 bq = *(const float4*)&w[(size_t)k2 * H + j];
  float4 o = {a.x + bq.x, a.y + bq.y, a.z + bq.z, a.w + bq.w};
  *(float4*)&wof[((size_t)l * KV + c) * H + j] = o;
}

// ------------------------------ GEMM 64x64x32 ------------------------------
// Split-K partial GEMM. A is [256, lda]; if NORM, A_logical = h*r[row]*wn[k].
// If GATHER, A column = ((k>>7)<<6)|(k&63) (repeat-KV). B normal [K,N] or
// BT [N,K]. Writes partial C for split blockIdx.z at Cp + z*256*N.
template <bool NORM, bool GATHER, bool BT, bool BOUND>
__global__ __launch_bounds__(256) void gemm64_k(
    const float* __restrict__ A, int lda,
    const float* __restrict__ rv, const float* __restrict__ wn,
    const float* __restrict__ Bm, int ldb,
    float* __restrict__ Cp, int N, int Kslice) {
  __shared__ __align__(16) float As[32][68];
  __shared__ __align__(16) float Bs[32][68];
  const int tid = threadIdx.x;
  const int tx = tid & 15, ty = tid >> 4;
  const int bm = blockIdx.y * 64;
  const int bn = blockIdx.x * 64;
  const int ks0 = blockIdx.z * Kslice;
  float4 acc[4];
#pragma unroll
  for (int i = 0; i < 4; ++i) acc[i] = float4{0.f, 0.f, 0.f, 0.f};

  for (int k0 = 0; k0 < Kslice; k0 += 32) {
    const int kbase = ks0 + k0;
#pragma unroll
    for (int s = 0; s < 2; ++s) {
      int slot = tid + s * 256;
      int rI = slot >> 3, c = slot & 7;
      int k = kbase + c * 4;
      int col = GATHER ? (((k >> 7) << 6) | (k & 63)) : k;
      float4 av = *(const float4*)&A[(size_t)(bm + rI) * lda + col];
      if (NORM) {
        float sc = rv[bm + rI];
        float4 wv = *(const float4*)&wn[k];
        av.x *= sc * wv.x; av.y *= sc * wv.y;
        av.z *= sc * wv.z; av.w *= sc * wv.w;
      }
      As[c * 4 + 0][rI] = av.x; As[c * 4 + 1][rI] = av.y;
      As[c * 4 + 2][rI] = av.z; As[c * 4 + 3][rI] = av.w;
    }
#pragma unroll
    for (int s = 0; s < 2; ++s) {
      int slot = tid + s * 256;
      if (!BT) {
        int kI = slot >> 4, c4 = slot & 15;
        float4 bv = *(const float4*)&Bm[(size_t)(kbase + kI) * ldb + bn + c4 * 4];
        *(float4*)&Bs[kI][c4 * 4] = bv;
      } else {
        int nI = slot >> 3, c = slot & 7;
        int n = bn + nI;
        float4 bv = {0.f, 0.f, 0.f, 0.f};
        if (!BOUND || n < N)
          bv = *(const float4*)&Bm[(size_t)n * ldb + kbase + c * 4];
        Bs[c * 4 + 0][nI] = bv.x; Bs[c * 4 + 1][nI] = bv.y;
        Bs[c * 4 + 2][nI] = bv.z; Bs[c * 4 + 3][nI] = bv.w;
      }
    }
    __syncthreads();
#pragma unroll
    for (int kk = 0; kk < 32; ++kk) {
      float4 a = *(const float4*)&As[kk][ty * 4];
      float4 b = *(const float4*)&Bs[kk][tx * 4];
      float ar[4] = {a.x, a.y, a.z, a.w};
#pragma unroll
      for (int i = 0; i < 4; ++i) {
        acc[i].x = fmaf(ar[i], b.x, acc[i].x);
        acc[i].y = fmaf(ar[i], b.y, acc[i].y);
        acc[i].z = fmaf(ar[i], b.z, acc[i].z);
        acc[i].w = fmaf(ar[i], b.w, acc[i].w);
      }
    }
    __syncthreads();
  }
  float* base = Cp + (size_t)blockIdx.z * 256 * N;
#pragma unroll
  for (int i = 0; i < 4; ++i) {
    int row = bm + ty * 4 + i;
    int colb = bn + tx * 4;
    if (!BOUND) {
      *(float4*)&base[(size_t)row * N + colb] = acc[i];
    } else {
      float vals[4] = {acc[i].x, acc[i].y, acc[i].z, acc[i].w};
      for (int j = 0; j < 4; ++j)
        if (colb + j < N) base[(size_t)row * N + colb + j] = vals[j];
    }
  }
}

// ---------------- fused gate/up GEMM, 64x64x32 joint, silu -----------------
// m = silu(x@Wg) * (x@Wu); x = h*r*wn fused in staging. Full K, no split.
// Thread = 4 rows x 4 cols of BOTH G and U = 32 FMA/kk vs 3 ds_read_b128.
// Double-buffered LDS + register prefetch: one barrier per k-tile, global
// loads for tile t+1 issue before compute of tile t (nt=32 deep pipeline).
// Grid (64,4) = 256 blocks. fmaf chain per output ascending-k, identical
// NORM/silu expressions -> bitwise-identical m.
__global__ __launch_bounds__(256) void gemm_gu_k(
    const float* __restrict__ hm, const float* __restrict__ rv,
    const float* __restrict__ wn,
    const float* __restrict__ Bg, const float* __restrict__ Bu,
    float* __restrict__ Mo) {
  __shared__ __align__(16) float As[2][32][68];
  __shared__ __align__(16) float Gs[2][32][68];
  __shared__ __align__(16) float Us[2][32][68];
  const int tid = threadIdx.x;
  const int tx = tid & 15, ty = tid >> 4;
  const int bm = blockIdx.y * 64;
  const int bn = blockIdx.x * 64;
  float4 ag[4], au[4];
#pragma unroll
  for (int i = 0; i < 4; ++i) {
    ag[i] = float4{0.f, 0.f, 0.f, 0.f};
    au[i] = float4{0.f, 0.f, 0.f, 0.f};
  }

  float4 a_pre[2], g_pre[2], u_pre[2];

  auto load_regs = [&](int k0) {
#pragma unroll
    for (int s = 0; s < 2; ++s) {
      const int slot = tid + s * 256;
      const int rI = slot >> 3, c = slot & 7;
      const int k = k0 + c * 4;
      float4 av = *(const float4*)&hm[(size_t)(bm + rI) * H + k];
      const float sc = rv[bm + rI];
      const float4 wv = *(const float4*)&wn[k];
      av.x *= sc * wv.x; av.y *= sc * wv.y;
      av.z *= sc * wv.z; av.w *= sc * wv.w;
      a_pre[s] = av;
      const int kI = slot >> 4, c4 = slot & 15;
      g_pre[s] = *(const float4*)&Bg[(size_t)(k0 + kI) * I + bn + c4 * 4];
      u_pre[s] = *(const float4*)&Bu[(size_t)(k0 + kI) * I + bn + c4 * 4];
    }
  };
  auto store_lds = [&](int p) {
#pragma unroll
    for (int s = 0; s < 2; ++s) {
      const int slot = tid + s * 256;
      const int rI = slot >> 3, c = slot & 7;
      As[p][c * 4 + 0][rI] = a_pre[s].x;
      As[p][c * 4 + 1][rI] = a_pre[s].y;
      As[p][c * 4 + 2][rI] = a_pre[s].z;
      As[p][c * 4 + 3][rI] = a_pre[s].w;
      const int kI = slot >> 4, c4 = slot & 15;
      *(float4*)&Gs[p][kI][c4 * 4] = g_pre[s];
      *(float4*)&Us[p][kI][c4 * 4] = u_pre[s];
    }
  };

  load_regs(0);
  store_lds(0);
  __syncthreads();
  int p = 0;
  for (int k0 = 0; k0 < H; k0 += 32) {
    if (k0 + 32 < H) load_regs(k0 + 32);  // global loads overlap compute below
#pragma unroll
    for (int kk = 0; kk < 32; ++kk) {
      const float4 a = *(const float4*)&As[p][kk][ty * 4];
      const float4 g = *(const float4*)&Gs[p][kk][tx * 4];
      const float4 u = *(const float4*)&Us[p][kk][tx * 4];
      const float ar[4] = {a.x, a.y, a.z, a.w};
#pragma unroll
      for (int i = 0; i < 4; ++i) {
        ag[i].x = fmaf(ar[i], g.x, ag[i].x);
        ag[i].y = fmaf(ar[i], g.y, ag[i].y);
        ag[i].z = fmaf(ar[i], g.z, ag[i].z);
        ag[i].w = fmaf(ar[i], g.w, ag[i].w);
        au[i].x = fmaf(ar[i], u.x, au[i].x);
        au[i].y = fmaf(ar[i], u.y, au[i].y);
        au[i].z = fmaf(ar[i], u.z, au[i].z);
        au[i].w = fmaf(ar[i], u.w, au[i].w);
      }
    }
    if (k0 + 32 < H) store_lds(p ^ 1);  // writes to idle buffer, pre-barrier
    __syncthreads();
    p ^= 1;
  }
#pragma unroll
  for (int i = 0; i < 4; ++i) {
    const int row = bm + ty * 4 + i;
    const int col = bn + tx * 4;
    const float gv[4] = {ag[i].x, ag[i].y, ag[i].z, ag[i].w};
    const float uv[4] = {au[i].x, au[i].y, au[i].z, au[i].w};
    float o[4];
#pragma unroll
    for (int j = 0; j < 4; ++j) {
      const float s = 1.0f / (1.0f + expf(-gv[j]));
      o[j] = gv[j] * s * uv[j];
    }
    *(float4*)&Mo[(size_t)row * I + col] = *(const float4*)&o[0];
  }
}

// ------------------------------ reductions ---------------------------------
__global__ __launch_bounds__(256) void red_v_k(const float* __restrict__ part,
                                               float* __restrict__ v, int S) {
  int i4 = (blockIdx.x * 256 + threadIdx.x) * 4;
  float4 s = {0.f, 0.f, 0.f, 0.f};
  for (int ss = 0; ss < S; ++ss) {
    float4 p = *(const float4*)&part[(size_t)ss * (256 * KV) + i4];
    s.x += p.x; s.y += p.y; s.z += p.z; s.w += p.w;
  }
  *(float4*)&v[i4] = s;
}

// h += sum(partials) ; r[b] = rsqrt(mean(h^2)+eps). Block per row, N=1024.
__global__ __launch_bounds__(256) void red_add_rms_k(const float* __restrict__ part,
                                                     float* __restrict__ h,
                                                     float* __restrict__ r, int S) {
  int b = blockIdx.x, tid = threadIdx.x;
  size_t off = (size_t)b * H + tid * 4;
  float4 a = *(const float4*)&h[off];
  for (int ss = 0; ss < S; ++ss) {
    float4 p = *(const float4*)&part[(size_t)ss * (256 * H) + off];
    a.x += p.x; a.y += p.y; a.z += p.z; a.w += p.w;
  }
  *(float4*)&h[off] = a;
  float s = a.x * a.x + a.y * a.y + a.z * a.z + a.w * a.w;
  for (int o = 32; o > 0; o >>= 1) s += __shfl_down(s, o, 64);
  __shared__ float red[4];
  if ((tid & 63) == 0) red[tid >> 6] = s;
  __syncthreads();
  if (tid == 0) {
    float t = red[0] + red[1] + red[2] + red[3];
    r[b] = 1.0f / sqrtf(t * (1.0f / 1024.0f) + 1e-6f);
  }
}

// --------------------------- head: reduce+reppen+sample+embed --------------
__global__ __launch_bounds__(256) void head_k(
    const float* __restrict__ part, int S,
    const int* __restrict__ gh, const int* __restrict__ gen_step_p,
    int step, const float* __restrict__ embed_next,
    float* __restrict__ h, float* __restrict__ r,
    int* __restrict__ out) {
  constexpr int TOPK = 30;
  constexpr int KMAX = 64;
  const int b = blockIdx.x, tid = threadIdx.x;
  __shared__ float sl[V];
  __shared__ float rv_[256]; __shared__ int ri[256];
  __shared__ float topv[TOPK]; __shared__ int topi[TOPK];
  __shared__ float kv[KMAX]; __shared__ int ki[KMAX]; __shared__ int keepf[KMAX];
  __shared__ uint32_t skey[2];
  __shared__ int scnt, sn, stok;
  __shared__ float redf[4];

  if (tid == 0) {
    uint32_t o0, o1;
    tf2x32(0u, 1234u, 0u, (uint32_t)step, o0, o1);
    skey[0] = o0; skey[1] = o1;
    scnt = 0;
  }
  // sum split-K partials of the logits row
  for (int v = tid; v < V; v += 256) {
    float s = 0.f;
    for (int ss = 0; ss < S; ++ss)
      s += part[(size_t)ss * (256 * V) + (size_t)b * V + v];
    sl[v] = s;
  }
  __syncthreads();
  // repetition penalty (read-all-then-write .set semantics; dup writes identical)
  int gs = *gen_step_p;
  int cnt = gs < 50 ? gs : 50;
  int start = gs - cnt;
  int tkn = -1; float val = 0.f;
  if (tid < cnt) {
    tkn = gh[(size_t)b * 200 * C + (size_t)(start + tid) * C + step];
    val = sl[tkn];
  }
  __syncthreads();
  if (tid < cnt) sl[tkn] = (val < 0.f) ? val * 1.1f : val / 1.1f;
  __syncthreads();
  for (int v = tid; v < V; v += 256) sl[v] = sl[v] / 0.8f;
  __syncthreads();

  // iterative top-30 (argmax, lowest-index tiebreak)
  for (int it = 0; it < TOPK; ++it) {
    float bv = -INFINITY; int bi = 0x7fffffff;
    for (int v = tid; v < V; v += 256) {
      float x = sl[v];
      if (x > bv) { bv = x; bi = v; }
    }
    rv_[tid] = bv; ri[tid] = bi;
    __syncthreads();
    for (int s = 128; s > 0; s >>= 1) {
      if (tid < s) {
        float ov = rv_[tid + s]; int oi = ri[tid + s];
        if (ov > rv_[tid] || (ov == rv_[tid] && oi < ri[tid])) { rv_[tid] = ov; ri[tid] = oi; }
      }
      __syncthreads();
    }
    if (tid == 0) { topv[it] = rv_[0]; topi[it] = ri[0]; sl[ri[0]] = -INFINITY; }
    __syncthreads();
  }
  if (tid < TOPK) sl[topi[tid]] = topv[tid];
  __syncthreads();
  const float thr = topv[TOPK - 1];
  for (int v = tid; v < V; v += 256) {
    if (sl[v] >= thr) {
      int p = atomicAdd(&scnt, 1);
      if (p < KMAX) { kv[p] = sl[v]; ki[p] = v; }
    }
  }
  __syncthreads();

  if (tid == 0) {
    int n = scnt < KMAX ? scnt : KMAX;
    for (int a = 1; a < n; ++a) {  // stable ascending (value,index) sort
      float cv = kv[a]; int ci = ki[a];
      int p = a - 1;
      while (p >= 0 && (kv[p] > cv || (kv[p] == cv && ki[p] > ci))) {
        kv[p + 1] = kv[p]; ki[p + 1] = ki[p]; --p;
      }
      kv[p + 1] = cv; ki[p + 1] = ci;
    }
    float mx = kv[n - 1];
    float denom = 0.f;
    for (int j = 0; j < n; ++j) denom += expf(kv[j] - mx);
    float c = 0.f;
    for (int j = 0; j < n; ++j) {
      float p = expf(kv[j] - mx) / denom;
      c += p;
      keepf[j] = ((double)c > 0.4) ? 1 : 0;
    }
    sn = n;
  }
  __syncthreads();

  int n = sn;
  rv_[tid] = -INFINITY; ri[tid] = 0x7fffffff;
  if (tid < n && keepf[tid]) {
    uint32_t idx = (uint32_t)b * (uint32_t)V + (uint32_t)ki[tid];
    float g = gumbel_for(skey[0], skey[1], idx);
    rv_[tid] = kv[tid] + g;
    ri[tid] = ki[tid];
  }
  __syncthreads();
  for (int s = 128; s > 0; s >>= 1) {
    if (tid < s) {
      float ov = rv_[tid + s]; int oi = ri[tid + s];
      if (ov > rv_[tid] || (ov == rv_[tid] && oi < ri[tid])) { rv_[tid] = ov; ri[tid] = oi; }
    }
    __syncthreads();
  }
  if (tid == 0) {
    stok = ri[0];
    out[(size_t)b * C + step] = ri[0];
  }
  __syncthreads();

  // next-step embedding + rms scale, fused
  if (embed_next != nullptr) {
    int tok = stok;
    float4 e = *(const float4*)&embed_next[(size_t)tok * H + tid * 4];
    *(float4*)&h[(size_t)b * H + tid * 4] = e;
    float s = e.x * e.x + e.y * e.y + e.z * e.z + e.w * e.w;
    for (int o = 32; o > 0; o >>= 1) s += __shfl_down(s, o, 64);
    if ((tid & 63) == 0) redf[tid >> 6] = s;
    __syncthreads();
    if (tid == 0) {
      float t = redf[0] + redf[1] + redf[2] + redf[3];
      r[b] = 1.0f / sqrtf(t * (1.0f / 1024.0f) + 1e-6f);
    }
  }
}

// ------------------------------ launch -------------------------------------
extern "C" void kernel_launch(void* const* d_in, const int* in_sizes, int n_in,
                              void* d_out, int out_size, void* d_ws, size_t ws_size,
                              hipStream_t stream) {
  const float* backbone = (const float*)d_in[0];
  const int*   gh       = (const int*)d_in[1];
  const int*   gen_step = (const int*)d_in[2];
  const float* embed    = (const float*)d_in[3];
  const float* lm       = (const float*)d_in[4];
  const float* w_in     = (const float*)d_in[5];
  // d_in[6]=w_q, d_in[7]=w_k, d_in[9]=q_norm, d_in[10]=k_norm dead (seq_len==1)
  const float* w_v      = (const float*)d_in[8];
  const float* w_o      = (const float*)d_in[11];
  const float* w_post   = (const float*)d_in[12];
  const float* w_g      = (const float*)d_in[13];
  const float* w_u      = (const float*)d_in[14];
  const float* w_d      = (const float*)d_in[15];
  const float* fnorm    = (const float*)d_in[16];
  int* out = (int*)d_out;
  float* ws = (float*)d_ws;

  // big path needs 5,642,752 floats (~22.6MB); small path fits proven 7.87MB
  const bool big = ws_size >= (size_t)22600000;
  float* h    = ws;                                   // 262144
  float* v    = ws + 262144;                          // 131072
  float* m    = ws + 393216;                          // 1048576
  float* wof  = big ? ws + 1441792 : nullptr;         // 2097152 (big only)
  float* part = big ? ws + 3538944 : ws + 1441792;    // 2103296 / 524288
  float* r    = big ? ws + 5642240 : ws + 1966080;    // 256

  const int S1 = big ? 16 : 4;
  const int S2 = big ? 8 : 2;
  const int S4 = big ? 8 : 2;
  const int S5 = big ? 8 : 1;

  copy_rms_k<<<dim3(256), dim3(256), 0, stream>>>(backbone, h, r);
  if (big) fold_k<<<dim3(2048), dim3(256), 0, stream>>>(w_o, wof);

  for (int i = 0; i < C; ++i) {
    for (int l = 0; l < L; ++l) {
      // v = rms(h)*wi @ Wv   [256,1024]x[1024,512], split-K
      gemm64_k<true, false, false, false><<<dim3(8, 4, S1), dim3(256), 0, stream>>>(
          h, H, r, w_in + (size_t)l * H, w_v + (size_t)l * H * KV, KV,
          part, KV, H / S1);
      red_v_k<<<dim3(128), dim3(256), 0, stream>>>(part, v, S1);
      // h += v @ Wo' (folded, K=512) or gather path (small)
      if (big)
        gemm64_k<false, false, false, false><<<dim3(16, 4, S2), dim3(256), 0, stream>>>(
            v, KV, nullptr, nullptr, wof + (size_t)l * KV * H, H,
            part, H, KV / S2);
      else
        gemm64_k<false, true, false, false><<<dim3(16, 4, S2), dim3(256), 0, stream>>>(
            v, KV, nullptr, nullptr, w_o + (size_t)l * H * H, H,
            part, H, H / S2);
      red_add_rms_k<<<dim3(256), dim3(256), 0, stream>>>(part, h, r, S2);
      // m = silu(x2@Wg)*(x2@Wu), x2 = rms(h)*wp fused; no split, silu fused
      gemm_gu_k<<<dim3(64, 4), dim3(256), 0, stream>>>(
          h, r, w_post + (size_t)l * H,
          w_g + (size_t)l * H * I, w_u + (size_t)l * H * I, m);
      // h += m @ Wd   [256,4096]x[4096,1024], split-K
      gemm64_k<false, false, false, false><<<dim3(16, 4, S4), dim3(256), 0, stream>>>(
          m, I, nullptr, nullptr, w_d + (size_t)l * I * H, H,
          part, H, I / S4);
      red_add_rms_k<<<dim3(256), dim3(256), 0, stream>>>(part, h, r, S4);
    }
    // logits partials = rms(h)*fnorm @ lm[i]^T  (BT, N=1027 bounds)
    gemm64_k<true, false, true, true><<<dim3(17, 4, S5), dim3(256), 0, stream>>>(
        h, H, r, fnorm, lm + (size_t)i * V * H, H, part, V, H / S5);
    head_k<<<dim3(256), dim3(256), 0, stream>>>(
        part, S5, gh, gen_step, i,
        (i < C - 1) ? embed + (size_t)(i + 1) * V * H : nullptr,
        h, r, out);
  }
}